// Round 2
// baseline (200.907 us; speedup 1.0000x reference)
//
#include <hip/hip_runtime.h>
#include <hip/hip_bf16.h>

// ParallelExperts: per-expert LayerNorm -> Linear(1024->4096) -> tanh-GELU
// E=16 experts, 512 tokens each (balanced), fp32 in/out, bf16 MFMA inside.

#define E_EXP 16
#define T_TOK 8192
#define DIN   1024
#define DOUT  4096

typedef __bf16 bf16;
typedef __bf16 bf16x4v __attribute__((ext_vector_type(4)));
typedef __bf16 bf16x8v __attribute__((ext_vector_type(8)));
typedef float  f32x4   __attribute__((ext_vector_type(4)));

typedef __attribute__((address_space(1))) void gvoid;
typedef __attribute__((address_space(3))) void lvoid;

// ---------------- LayerNorm -> bf16 (one block per token) ----------------
__global__ __launch_bounds__(256) void ln_bf16_kernel(
    const float* __restrict__ x, const float* __restrict__ gamma,
    const float* __restrict__ beta, bf16* __restrict__ xn) {
  const int t    = blockIdx.x;
  const int e    = t >> 9;            // 512 tokens per expert
  const int tid  = threadIdx.x;
  const float4 xv = reinterpret_cast<const float4*>(x + (size_t)t * DIN)[tid];
  float s  = xv.x + xv.y + xv.z + xv.w;
  float s2 = xv.x * xv.x + xv.y * xv.y + xv.z * xv.z + xv.w * xv.w;
#pragma unroll
  for (int o = 32; o > 0; o >>= 1) {
    s  += __shfl_xor(s,  o, 64);
    s2 += __shfl_xor(s2, o, 64);
  }
  __shared__ float red[8];
  const int lane = tid & 63, wid = tid >> 6;
  if (lane == 0) { red[wid] = s; red[4 + wid] = s2; }
  __syncthreads();
  s  = red[0] + red[1] + red[2] + red[3];
  s2 = red[4] + red[5] + red[6] + red[7];
  const float mu  = s * (1.0f / DIN);
  const float var = s2 * (1.0f / DIN) - mu * mu;
  const float inv = rsqrtf(var + 1e-5f);
  const float4 g = reinterpret_cast<const float4*>(gamma + (size_t)e * DIN)[tid];
  const float4 b = reinterpret_cast<const float4*>(beta  + (size_t)e * DIN)[tid];
  bf16x4v o;
  o[0] = (bf16)((xv.x - mu) * inv * g.x + b.x);
  o[1] = (bf16)((xv.y - mu) * inv * g.y + b.y);
  o[2] = (bf16)((xv.z - mu) * inv * g.z + b.z);
  o[3] = (bf16)((xv.w - mu) * inv * g.w + b.w);
  *reinterpret_cast<bf16x4v*>(xn + (size_t)t * DIN + tid * 4) = o;
}

// ---------------- grouped GEMM: C = GELU(xn @ W[e] + b[e]) ----------------
// 128x128 tile, BK=32, 4 waves (2x2), 4x4 16x16x32 fragments per wave.
// Double-buffered LDS, single barrier per K-step.
// B (W, fp32 [k][n]) is gathered column-wise per lane (coalesced across the
// wave), cast to bf16 in-register, and written as two ds_write_b128 per
// thread into the transposed [n][k] LDS tile -> bank-conflict-free.
#define BM 128
#define BN 128
#define BK 32
#define KPAD 40   // [n][k] LDS row stride in bf16 (80 B = 16B-aligned rows)

__global__ __launch_bounds__(256) void grouped_gemm_kernel(
    const bf16* __restrict__ xn, const float* __restrict__ W,
    const float* __restrict__ bias, float* __restrict__ out) {
  __shared__ bf16 Alds[2][BM * BK];     // 2 x 8 KB, [m][32] linear
  __shared__ bf16 Blds[2][BN * KPAD];   // 2 x 10 KB, [n][40] transposed

  const int tid    = threadIdx.x;
  const int lane   = tid & 63;
  const int wid    = tid >> 6;
  const int warp_m = wid >> 1;       // 0..1
  const int warp_n = wid & 1;        // 0..1
  const int ntile  = blockIdx.x;     // 0..31
  const int mtile  = blockIdx.y;     // 0..63
  const int e      = mtile >> 2;     // 4 m-tiles per expert
  const int t0     = mtile * BM;
  const int n0     = ntile * BN;

  f32x4 acc[4][4];
#pragma unroll
  for (int i = 0; i < 4; ++i)
#pragma unroll
    for (int j = 0; j < 4; ++j)
      acc[i][j] = (f32x4){0.f, 0.f, 0.f, 0.f};

  const bf16*  Abase = xn + (size_t)t0 * DIN;
  const float* Wbase = W + (size_t)e * DIN * DOUT + n0;

  const int bn  = tid & 127;         // B: n column this thread owns
  const int bk0 = (tid >> 7) * 16;   // B: first k this thread covers (0 or 16)

  float w0[8], w1[8];                // B staging regs (k = bk0..bk0+15)

#define STAGE_A(buf, k0)                                                      \
  {                                                                           \
    _Pragma("unroll")                                                         \
    for (int c = 0; c < 2; ++c) {                                             \
      const int cidx = wid * 2 + c;                                           \
      const int row  = cidx * 16 + (lane >> 2);                               \
      const bf16* g  = Abase + (size_t)row * DIN + (k0) + (lane & 3) * 8;     \
      __builtin_amdgcn_global_load_lds((gvoid*)g,                             \
                                       (lvoid*)&Alds[buf][cidx * 512], 16, 0, 0); \
    }                                                                         \
  }

#define LOAD_B(k0)                                                            \
  {                                                                           \
    _Pragma("unroll")                                                         \
    for (int r = 0; r < 8; ++r)                                               \
      w0[r] = Wbase[(size_t)((k0) + bk0 + r) * DOUT + bn];                    \
    _Pragma("unroll")                                                         \
    for (int r = 0; r < 8; ++r)                                               \
      w1[r] = Wbase[(size_t)((k0) + bk0 + 8 + r) * DOUT + bn];                \
  }

#define WRITE_B(buf)                                                          \
  {                                                                           \
    bf16x8v v0, v1;                                                           \
    _Pragma("unroll")                                                         \
    for (int r = 0; r < 8; ++r) v0[r] = (bf16)w0[r];                          \
    _Pragma("unroll")                                                         \
    for (int r = 0; r < 8; ++r) v1[r] = (bf16)w1[r];                          \
    *(bf16x8v*)&Blds[buf][bn * KPAD + bk0]     = v0;                          \
    *(bf16x8v*)&Blds[buf][bn * KPAD + bk0 + 8] = v1;                          \
  }

  // ---- prologue: stage K-tile 0 into buffer 0 ----
  STAGE_A(0, 0);
  LOAD_B(0);
  WRITE_B(0);
  __syncthreads();   // barrier drain also completes the A global_load_lds

  for (int ks = 0; ks < DIN / BK; ++ks) {
    const int buf = ks & 1;
    const bool more = (ks + 1) < (DIN / BK);
    if (more) {
      STAGE_A(buf ^ 1, (ks + 1) * BK);   // async A -> other LDS buffer
      LOAD_B((ks + 1) * BK);             // B -> registers (latency hidden by MFMA)
    }

    // --- fragments + MFMA on current buffer ---
    bf16x8v af[4], bfr[4];
#pragma unroll
    for (int mi = 0; mi < 4; ++mi)
      af[mi] = *reinterpret_cast<const bf16x8v*>(
          &Alds[buf][(warp_m * 64 + mi * 16 + (lane & 15)) * BK + (lane >> 4) * 8]);
#pragma unroll
    for (int ni = 0; ni < 4; ++ni)
      bfr[ni] = *reinterpret_cast<const bf16x8v*>(
          &Blds[buf][(warp_n * 64 + ni * 16 + (lane & 15)) * KPAD + (lane >> 4) * 8]);
#pragma unroll
    for (int mi = 0; mi < 4; ++mi)
#pragma unroll
      for (int ni = 0; ni < 4; ++ni)
        acc[mi][ni] = __builtin_amdgcn_mfma_f32_16x16x32_bf16(
            af[mi], bfr[ni], acc[mi][ni], 0, 0, 0);

    if (more) WRITE_B(buf ^ 1);          // cvt + 2x ds_write_b128, other buffer
    __syncthreads();
  }

  // --- epilogue: + bias, tanh-GELU (jax.nn.gelu approximate=True), fp32 out ---
  // D frag: lane holds D[row = (lane>>4)*4 + r][col = lane&15]
  const float* be = bias + (size_t)e * DOUT;
#pragma unroll
  for (int ni = 0; ni < 4; ++ni) {
    const int col = n0 + warp_n * 64 + ni * 16 + (lane & 15);
    const float bc = be[col];
#pragma unroll
    for (int mi = 0; mi < 4; ++mi) {
#pragma unroll
      for (int rr = 0; rr < 4; ++rr) {
        const int row = t0 + warp_m * 64 + mi * 16 + (lane >> 4) * 4 + rr;
        float v = acc[mi][ni][rr] + bc;
        const float u = 0.7978845608028654f * (v + 0.044715f * v * v * v);
        v = 0.5f * v * (1.0f + tanhf(u));
        out[(size_t)row * DOUT + col] = v;
      }
    }
  }
}

extern "C" void kernel_launch(void* const* d_in, const int* in_sizes, int n_in,
                              void* d_out, int out_size, void* d_ws, size_t ws_size,
                              hipStream_t stream) {
  const float* x     = (const float*)d_in[0];
  // d_in[1] = expert_frequency: balanced by construction (512 each) -> unused
  const float* gamma = (const float*)d_in[2];
  const float* beta  = (const float*)d_in[3];
  const float* W     = (const float*)d_in[4];
  const float* bias  = (const float*)d_in[5];
  float* out = (float*)d_out;
  bf16* xn   = (bf16*)d_ws;    // 8192*1024 bf16 = 16 MiB scratch

  hipLaunchKernelGGL(ln_bf16_kernel, dim3(T_TOK), dim3(256), 0, stream,
                     x, gamma, beta, xn);
  hipLaunchKernelGGL(grouped_gemm_kernel, dim3(DOUT / BN, T_TOK / BM), dim3(256),
                     0, stream, xn, W, bias, out);
}

// Round 3
// 196.266 us; speedup vs baseline: 1.0236x; 1.0236x over previous
//
#include <hip/hip_runtime.h>
#include <hip/hip_bf16.h>

// ParallelExperts: per-expert LayerNorm -> Linear(1024->4096) -> tanh-GELU
// E=16 experts, 512 tokens each (balanced), fp32 in/out, bf16 MFMA inside.

#define E_EXP 16
#define T_TOK 8192
#define DIN   1024
#define DOUT  4096

typedef __bf16 bf16;
typedef __bf16 bf16x4v __attribute__((ext_vector_type(4)));
typedef __bf16 bf16x8v __attribute__((ext_vector_type(8)));
typedef float  f32x4   __attribute__((ext_vector_type(4)));

typedef __attribute__((address_space(1))) void gvoid;
typedef __attribute__((address_space(3))) void lvoid;

// ---------------- LayerNorm -> bf16 (one block per token) ----------------
__global__ __launch_bounds__(256) void ln_bf16_kernel(
    const float* __restrict__ x, const float* __restrict__ gamma,
    const float* __restrict__ beta, bf16* __restrict__ xn) {
  const int t    = blockIdx.x;
  const int e    = t >> 9;            // 512 tokens per expert
  const int tid  = threadIdx.x;
  const float4 xv = reinterpret_cast<const float4*>(x + (size_t)t * DIN)[tid];
  float s  = xv.x + xv.y + xv.z + xv.w;
  float s2 = xv.x * xv.x + xv.y * xv.y + xv.z * xv.z + xv.w * xv.w;
#pragma unroll
  for (int o = 32; o > 0; o >>= 1) {
    s  += __shfl_xor(s,  o, 64);
    s2 += __shfl_xor(s2, o, 64);
  }
  __shared__ float red[8];
  const int lane = tid & 63, wid = tid >> 6;
  if (lane == 0) { red[wid] = s; red[4 + wid] = s2; }
  __syncthreads();
  s  = red[0] + red[1] + red[2] + red[3];
  s2 = red[4] + red[5] + red[6] + red[7];
  const float mu  = s * (1.0f / DIN);
  const float var = s2 * (1.0f / DIN) - mu * mu;
  const float inv = rsqrtf(var + 1e-5f);
  const float4 g = reinterpret_cast<const float4*>(gamma + (size_t)e * DIN)[tid];
  const float4 b = reinterpret_cast<const float4*>(beta  + (size_t)e * DIN)[tid];
  bf16x4v o;
  o[0] = (bf16)((xv.x - mu) * inv * g.x + b.x);
  o[1] = (bf16)((xv.y - mu) * inv * g.y + b.y);
  o[2] = (bf16)((xv.z - mu) * inv * g.z + b.z);
  o[3] = (bf16)((xv.w - mu) * inv * g.w + b.w);
  *reinterpret_cast<bf16x4v*>(xn + (size_t)t * DIN + tid * 4) = o;
}

// ---------------- grouped GEMM: C = GELU(xn @ W[e] + b[e]) ----------------
// 128x128 tile, BK=32, 4 waves (2x2), 4x4 16x16x32 fragments per wave.
// 2-deep software pipeline with RAW s_barrier + counted vmcnt so B loads
// (tile k+2) stay in flight across barriers (T3/T4-lite). A is staged via
// global_load_lds; B is column-gathered to regs, cvt'd, ds_write_b128'd
// into the transposed [n][KPAD] LDS tile one iteration after issue.
#define BM 128
#define BN 128
#define BK 32
#define NK (DIN / BK)   // 32 K-steps
#define KPAD 40         // [n][k] LDS row stride in bf16 (80 B, 16B-aligned)

#define SCHED_FENCE __builtin_amdgcn_sched_barrier(0)

__global__ __launch_bounds__(256, 3) void grouped_gemm_kernel(
    const bf16* __restrict__ xn, const float* __restrict__ W,
    const float* __restrict__ bias, float* __restrict__ out) {
  __shared__ bf16 Alds[2][BM * BK];     // 2 x 8 KB, [m][32] linear
  __shared__ bf16 Blds[2][BN * KPAD];   // 2 x 10 KB, [n][40] transposed

  const int tid    = threadIdx.x;
  const int lane   = tid & 63;
  const int wid    = tid >> 6;
  const int warp_m = wid >> 1;       // 0..1
  const int warp_n = wid & 1;        // 0..1
  const int ntile  = blockIdx.x;     // 0..31
  const int mtile  = blockIdx.y;     // 0..63
  const int e      = mtile >> 2;     // 4 m-tiles per expert
  const int t0     = mtile * BM;
  const int n0     = ntile * BN;

  f32x4 acc[4][4];
#pragma unroll
  for (int i = 0; i < 4; ++i)
#pragma unroll
    for (int j = 0; j < 4; ++j)
      acc[i][j] = (f32x4){0.f, 0.f, 0.f, 0.f};

  const bf16*  Abase = xn + (size_t)t0 * DIN;
  const float* Wbase = W + (size_t)e * DIN * DOUT + n0;

  const int bn  = tid & 127;         // B: n column this thread owns
  const int bk0 = (tid >> 7) * 16;   // B: first k this thread covers (0 or 16)

  float wA[16], wB[16];              // two B register sets (2-deep pipeline)

#define STAGE_A(buf, k0)                                                      \
  {                                                                           \
    _Pragma("unroll")                                                         \
    for (int c = 0; c < 2; ++c) {                                             \
      const int cidx = wid * 2 + c;                                           \
      const int row  = cidx * 16 + (lane >> 2);                               \
      const bf16* g  = Abase + (size_t)row * DIN + (k0) + (lane & 3) * 8;     \
      __builtin_amdgcn_global_load_lds((gvoid*)g,                             \
                                       (lvoid*)&Alds[buf][cidx * 512], 16, 0, 0); \
    }                                                                         \
  }

#define LOAD_B(wreg, k0)                                                      \
  {                                                                           \
    _Pragma("unroll")                                                         \
    for (int r = 0; r < 16; ++r)                                              \
      wreg[r] = Wbase[(size_t)((k0) + bk0 + r) * DOUT + bn];                  \
  }

#define WRITE_B(wreg, buf)                                                    \
  {                                                                           \
    bf16x8v v0, v1;                                                           \
    _Pragma("unroll")                                                         \
    for (int r = 0; r < 8; ++r) v0[r] = (bf16)wreg[r];                        \
    _Pragma("unroll")                                                         \
    for (int r = 0; r < 8; ++r) v1[r] = (bf16)wreg[r + 8];                    \
    *(bf16x8v*)&Blds[buf][bn * KPAD + bk0]     = v0;                          \
    *(bf16x8v*)&Blds[buf][bn * KPAD + bk0 + 8] = v1;                          \
  }

// One K-step. C = compile-time buffer index (0/1). WL = reg set receiving
// tile KS+2's loads; WW = reg set (tile KS+1) written to LDS buf C^1.
// Steady-state vmcnt at barrier: 16 B-loads (tile KS+2) stay in flight;
// A's 2 global_load_lds and all older B loads are drained.
#define K_ITER(KS, C, WL, WW)                                                 \
  {                                                                           \
    if ((KS) + 1 < NK) STAGE_A((C) ^ 1, ((KS) + 1) * BK);                     \
    SCHED_FENCE;                                                              \
    if ((KS) + 2 < NK) LOAD_B(WL, ((KS) + 2) * BK);                           \
    SCHED_FENCE;                                                              \
    {                                                                         \
      bf16x8v af[4], bfr[4];                                                  \
      _Pragma("unroll")                                                       \
      for (int mi = 0; mi < 4; ++mi)                                          \
        af[mi] = *reinterpret_cast<const bf16x8v*>(                           \
            &Alds[C][(warp_m * 64 + mi * 16 + (lane & 15)) * BK +             \
                     (lane >> 4) * 8]);                                       \
      _Pragma("unroll")                                                       \
      for (int ni = 0; ni < 4; ++ni)                                          \
        bfr[ni] = *reinterpret_cast<const bf16x8v*>(                          \
            &Blds[C][(warp_n * 64 + ni * 16 + (lane & 15)) * KPAD +           \
                     (lane >> 4) * 8]);                                       \
      _Pragma("unroll")                                                       \
      for (int mi = 0; mi < 4; ++mi)                                          \
        _Pragma("unroll")                                                     \
        for (int ni = 0; ni < 4; ++ni)                                        \
          acc[mi][ni] = __builtin_amdgcn_mfma_f32_16x16x32_bf16(              \
              af[mi], bfr[ni], acc[mi][ni], 0, 0, 0);                         \
    }                                                                         \
    SCHED_FENCE;                                                              \
    if ((KS) + 1 < NK) {                                                      \
      WRITE_B(WW, (C) ^ 1);                                                   \
      if ((KS) + 2 < NK)                                                      \
        asm volatile("s_waitcnt vmcnt(16)" ::: "memory");                     \
      else                                                                    \
        asm volatile("s_waitcnt vmcnt(0)" ::: "memory");                      \
      asm volatile("s_waitcnt lgkmcnt(0)" ::: "memory");                      \
      __builtin_amdgcn_s_barrier();                                           \
      asm volatile("" ::: "memory");                                          \
    }                                                                         \
  }

  // ---- prologue: tile0 -> buf0 (A async + B via regs), tile1 B in flight ----
  LOAD_B(wA, 0);                    // tile 0 -> regs (oldest 16 VMEM)
  SCHED_FENCE;
  STAGE_A(0, 0);                    // tile 0 A -> buf 0 (2 VMEM)
  SCHED_FENCE;
  LOAD_B(wB, BK);                   // tile 1 -> regs (youngest 16 VMEM)
  SCHED_FENCE;
  WRITE_B(wA, 0);                   // compiler auto-waits tile0's 16 loads
  asm volatile("s_waitcnt vmcnt(16)" ::: "memory");  // A done; tile1 in flight
  asm volatile("s_waitcnt lgkmcnt(0)" ::: "memory");
  __builtin_amdgcn_s_barrier();
  asm volatile("" ::: "memory");

  for (int ks = 0; ks < NK; ks += 2) {
    K_ITER(ks,     0, wA, wB);
    K_ITER(ks + 1, 1, wB, wA);
  }

  // --- epilogue: + bias, tanh-GELU (jax.nn.gelu approximate=True), fp32 out ---
  // D frag: lane holds D[row = (lane>>4)*4 + r][col = lane&15]
  const float* be = bias + (size_t)e * DOUT;
#pragma unroll
  for (int ni = 0; ni < 4; ++ni) {
    const int col = n0 + warp_n * 64 + ni * 16 + (lane & 15);
    const float bc = be[col];
#pragma unroll
    for (int mi = 0; mi < 4; ++mi) {
#pragma unroll
      for (int rr = 0; rr < 4; ++rr) {
        const int row = t0 + warp_m * 64 + mi * 16 + (lane >> 4) * 4 + rr;
        float v = acc[mi][ni][rr] + bc;
        const float u = 0.7978845608028654f * (v + 0.044715f * v * v * v);
        v = 0.5f * v * (1.0f + tanhf(u));
        out[(size_t)row * DOUT + col] = v;
      }
    }
  }
}

extern "C" void kernel_launch(void* const* d_in, const int* in_sizes, int n_in,
                              void* d_out, int out_size, void* d_ws, size_t ws_size,
                              hipStream_t stream) {
  const float* x     = (const float*)d_in[0];
  // d_in[1] = expert_frequency: balanced by construction (512 each) -> unused
  const float* gamma = (const float*)d_in[2];
  const float* beta  = (const float*)d_in[3];
  const float* W     = (const float*)d_in[4];
  const float* bias  = (const float*)d_in[5];
  float* out = (float*)d_out;
  bf16* xn   = (bf16*)d_ws;    // 8192*1024 bf16 = 16 MiB scratch

  hipLaunchKernelGGL(ln_bf16_kernel, dim3(T_TOK), dim3(256), 0, stream,
                     x, gamma, beta, xn);
  hipLaunchKernelGGL(grouped_gemm_kernel, dim3(DOUT / BN, T_TOK / BM), dim3(256),
                     0, stream, xn, W, bias, out);
}

// Round 4
// 179.483 us; speedup vs baseline: 1.1194x; 1.0935x over previous
//
#include <hip/hip_runtime.h>
#include <hip/hip_bf16.h>

// ParallelExperts: per-expert LayerNorm -> Linear(1024->4096) -> tanh-GELU
// E=16 experts, 512 tokens each (balanced), fp32 in/out, bf16 MFMA inside.

#define E_EXP 16
#define T_TOK 8192
#define DIN   1024
#define DOUT  4096

typedef __bf16 bf16;
typedef __bf16 bf16x4v __attribute__((ext_vector_type(4)));
typedef __bf16 bf16x8v __attribute__((ext_vector_type(8)));
typedef float  f32x4   __attribute__((ext_vector_type(4)));

typedef __attribute__((address_space(1))) void gvoid;
typedef __attribute__((address_space(3))) void lvoid;

// ---------------- LayerNorm -> bf16 (one block per token) ----------------
__global__ __launch_bounds__(256) void ln_bf16_kernel(
    const float* __restrict__ x, const float* __restrict__ gamma,
    const float* __restrict__ beta, bf16* __restrict__ xn) {
  const int t    = blockIdx.x;
  const int e    = t >> 9;            // 512 tokens per expert
  const int tid  = threadIdx.x;
  const float4 xv = reinterpret_cast<const float4*>(x + (size_t)t * DIN)[tid];
  float s  = xv.x + xv.y + xv.z + xv.w;
  float s2 = xv.x * xv.x + xv.y * xv.y + xv.z * xv.z + xv.w * xv.w;
#pragma unroll
  for (int o = 32; o > 0; o >>= 1) {
    s  += __shfl_xor(s,  o, 64);
    s2 += __shfl_xor(s2, o, 64);
  }
  __shared__ float red[8];
  const int lane = tid & 63, wid = tid >> 6;
  if (lane == 0) { red[wid] = s; red[4 + wid] = s2; }
  __syncthreads();
  s  = red[0] + red[1] + red[2] + red[3];
  s2 = red[4] + red[5] + red[6] + red[7];
  const float mu  = s * (1.0f / DIN);
  const float var = s2 * (1.0f / DIN) - mu * mu;
  const float inv = rsqrtf(var + 1e-5f);
  const float4 g = reinterpret_cast<const float4*>(gamma + (size_t)e * DIN)[tid];
  const float4 b = reinterpret_cast<const float4*>(beta  + (size_t)e * DIN)[tid];
  bf16x4v o;
  o[0] = (bf16)((xv.x - mu) * inv * g.x + b.x);
  o[1] = (bf16)((xv.y - mu) * inv * g.y + b.y);
  o[2] = (bf16)((xv.z - mu) * inv * g.z + b.z);
  o[3] = (bf16)((xv.w - mu) * inv * g.w + b.w);
  *reinterpret_cast<bf16x4v*>(xn + (size_t)t * DIN + tid * 4) = o;
}

// ---------------- grouped GEMM: C = GELU(xn @ W[e] + b[e]) ----------------
// 128x128 tile, BK=32, 4 waves (2x2), 4x4 16x16x32 fragments per wave.
// Deep pipeline: A staged 2 tiles ahead into 3 LDS buffers (gload_lds
// completion deadline = 1 full iteration); B loaded 3 tiles ahead into 3
// register sets (load->use distance = 2 iterations, covers L3/HBM latency).
// Counted vmcnt at each barrier keeps 34 VMEM ops in flight (2 A + 32 B).
#define BM 128
#define BN 128
#define BK 32
#define NK (DIN / BK)   // 32 K-steps
#define KPAD 40         // [n][k] LDS row stride in bf16 (80 B, 16B-aligned)

#define SCHED_FENCE __builtin_amdgcn_sched_barrier(0)

__global__ __launch_bounds__(256, 3) void grouped_gemm_kernel(
    const bf16* __restrict__ xn, const float* __restrict__ W,
    const float* __restrict__ bias, float* __restrict__ out) {
  __shared__ bf16 Alds[3][BM * BK];     // 3 x 8 KB, [m][32] linear
  __shared__ bf16 Blds[2][BN * KPAD];   // 2 x 10 KB, [n][40] transposed

  const int tid    = threadIdx.x;
  const int lane   = tid & 63;
  const int wid    = tid >> 6;
  const int warp_m = wid >> 1;       // 0..1
  const int warp_n = wid & 1;        // 0..1
  const int ntile  = blockIdx.x;     // 0..31
  const int mtile  = blockIdx.y;     // 0..63
  const int e      = mtile >> 2;     // 4 m-tiles per expert
  const int t0     = mtile * BM;
  const int n0     = ntile * BN;

  f32x4 acc[4][4];
#pragma unroll
  for (int i = 0; i < 4; ++i)
#pragma unroll
    for (int j = 0; j < 4; ++j)
      acc[i][j] = (f32x4){0.f, 0.f, 0.f, 0.f};

  const bf16*  Abase = xn + (size_t)t0 * DIN;
  const float* Wbase = W + (size_t)e * DIN * DOUT + n0;

  const int bn  = tid & 127;         // B: n column this thread owns
  const int bk0 = (tid >> 7) * 16;   // B: first k this thread covers (0 or 16)

  float s0[16], s1[16], s2[16];      // three B register sets (3-deep pipeline)

#define STAGE_A(buf, k0)                                                      \
  {                                                                           \
    _Pragma("unroll")                                                         \
    for (int c = 0; c < 2; ++c) {                                             \
      const int cidx = wid * 2 + c;                                           \
      const int row  = cidx * 16 + (lane >> 2);                               \
      const bf16* g  = Abase + (size_t)row * DIN + (k0) + (lane & 3) * 8;     \
      __builtin_amdgcn_global_load_lds((gvoid*)g,                             \
                                       (lvoid*)&Alds[buf][cidx * 512], 16, 0, 0); \
    }                                                                         \
  }

#define LOAD_B(wreg, k0)                                                      \
  {                                                                           \
    _Pragma("unroll")                                                         \
    for (int r = 0; r < 16; ++r)                                              \
      wreg[r] = Wbase[(size_t)((k0) + bk0 + r) * DOUT + bn];                  \
  }

#define WRITE_B(wreg, buf)                                                    \
  {                                                                           \
    bf16x8v v0, v1;                                                           \
    _Pragma("unroll")                                                         \
    for (int r = 0; r < 8; ++r) v0[r] = (bf16)wreg[r];                        \
    _Pragma("unroll")                                                         \
    for (int r = 0; r < 8; ++r) v1[r] = (bf16)wreg[r + 8];                    \
    *(bf16x8v*)&Blds[buf][bn * KPAD + bk0]     = v0;                          \
    *(bf16x8v*)&Blds[buf][bn * KPAD + bk0 + 8] = v1;                          \
  }

// One K-step body. KS may be a runtime expression (LDS indices are computed
// addresses); SL/SW are compile-time register-set names (static indexing).
// Issue order: stage A(KS+2), load B(KS+3), MFMA(KS), write B(KS+1).
#define K_BODY(KS, SL, SW, STG, LDB, WRB)                                     \
  {                                                                           \
    const int ab = (KS) % 3;                                                  \
    if (STG) STAGE_A(((KS) + 2) % 3, ((KS) + 2) * BK);                        \
    SCHED_FENCE;                                                              \
    if (LDB) LOAD_B(SL, ((KS) + 3) * BK);                                     \
    SCHED_FENCE;                                                              \
    {                                                                         \
      bf16x8v af[4], bfr[4];                                                  \
      _Pragma("unroll")                                                       \
      for (int mi = 0; mi < 4; ++mi)                                          \
        af[mi] = *reinterpret_cast<const bf16x8v*>(                           \
            &Alds[ab][(warp_m * 64 + mi * 16 + (lane & 15)) * BK +            \
                      (lane >> 4) * 8]);                                      \
      _Pragma("unroll")                                                       \
      for (int ni = 0; ni < 4; ++ni)                                          \
        bfr[ni] = *reinterpret_cast<const bf16x8v*>(                          \
            &Blds[(KS) & 1][(warp_n * 64 + ni * 16 + (lane & 15)) * KPAD +    \
                            (lane >> 4) * 8]);                                \
      _Pragma("unroll")                                                       \
      for (int mi = 0; mi < 4; ++mi)                                          \
        _Pragma("unroll")                                                     \
        for (int ni = 0; ni < 4; ++ni)                                        \
          acc[mi][ni] = __builtin_amdgcn_mfma_f32_16x16x32_bf16(              \
              af[mi], bfr[ni], acc[mi][ni], 0, 0, 0);                         \
    }                                                                         \
    SCHED_FENCE;                                                              \
    if (WRB) WRITE_B(SW, ((KS) + 1) & 1);                                     \
  }

// Barrier with counted vmcnt: N VMEM ops stay in flight across the barrier.
#define BAR_VM(N)                                                             \
  {                                                                           \
    SCHED_FENCE;                                                              \
    asm volatile("s_waitcnt vmcnt(" #N ")" ::: "memory");                     \
    asm volatile("s_waitcnt lgkmcnt(0)" ::: "memory");                        \
    __builtin_amdgcn_s_barrier();                                             \
    asm volatile("" ::: "memory");                                            \
  }

  // ---- prologue: A tiles 0,1 staged; B tiles 0,1,2 loaded; B0 written ----
  STAGE_A(0, 0);                 // A t0 (2 VMEM)
  SCHED_FENCE;
  LOAD_B(s0, 0);                 // B t0 (16)
  SCHED_FENCE;
  STAGE_A(1, BK);                // A t1 (2)
  SCHED_FENCE;
  LOAD_B(s1, BK);                // B t1 (16)
  SCHED_FENCE;
  LOAD_B(s2, 2 * BK);            // B t2 (16)
  SCHED_FENCE;
  WRITE_B(s0, 0);                // auto-waits B t0 (drains A t0 as older)
  BAR_VM(34);                    // in flight: A t1 + B t1 + B t2

  // Steady state: iter ks loads sets[ks%3] <- tile ks+3, writes
  // sets[(ks+1)%3] (tile ks+1) -> Blds[(ks+1)&1], stages A tile ks+2.
  // At the barrier: A(ks+2)=2 + B(ks+2)=16 + B(ks+3)=16 = 34 in flight;
  // A(ks+1) and B-writes drained.
  for (int ks = 0; ks < 27; ks += 3) {
    K_BODY(ks,     s0, s1, 1, 1, 1); BAR_VM(34);
    K_BODY(ks + 1, s1, s2, 1, 1, 1); BAR_VM(34);
    K_BODY(ks + 2, s2, s0, 1, 1, 1); BAR_VM(34);
  }
  K_BODY(27, s0, s1, 1, 1, 1); BAR_VM(34);
  K_BODY(28, s1, s2, 1, 1, 1); BAR_VM(34);   // loads t31 (last), stages A t30
  K_BODY(29, s2, s0, 1, 0, 1); BAR_VM(18);   // stages A t31; A t30+B t31 fly
  K_BODY(30, s0, s1, 0, 0, 1); BAR_VM(0);    // writes B t31; drain all
  K_BODY(31, s1, s2, 0, 0, 0);               // final MFMA, no barrier

  // --- epilogue: + bias, tanh-GELU (jax.nn.gelu approximate=True), fp32 out ---
  // gelu(v) = 0.5 v (1 + tanh(u)) = v * sigmoid(2u) = v / (1 + exp(-2u))
  // D frag: lane holds D[row = (lane>>4)*4 + r][col = lane&15]
  const float* be = bias + (size_t)e * DOUT;
#pragma unroll
  for (int ni = 0; ni < 4; ++ni) {
    const int col = n0 + warp_n * 64 + ni * 16 + (lane & 15);
    const float bc = be[col];
#pragma unroll
    for (int mi = 0; mi < 4; ++mi) {
#pragma unroll
      for (int rr = 0; rr < 4; ++rr) {
        const int row = t0 + warp_m * 64 + mi * 16 + (lane >> 4) * 4 + rr;
        float v = acc[mi][ni][rr] + bc;
        const float u = 0.7978845608028654f * (v + 0.044715f * v * v * v);
        v = v / (1.0f + __expf(-2.0f * u));
        out[(size_t)row * DOUT + col] = v;
      }
    }
  }
}

extern "C" void kernel_launch(void* const* d_in, const int* in_sizes, int n_in,
                              void* d_out, int out_size, void* d_ws, size_t ws_size,
                              hipStream_t stream) {
  const float* x     = (const float*)d_in[0];
  // d_in[1] = expert_frequency: balanced by construction (512 each) -> unused
  const float* gamma = (const float*)d_in[2];
  const float* beta  = (const float*)d_in[3];
  const float* W     = (const float*)d_in[4];
  const float* bias  = (const float*)d_in[5];
  float* out = (float*)d_out;
  bf16* xn   = (bf16*)d_ws;    // 8192*1024 bf16 = 16 MiB scratch

  hipLaunchKernelGGL(ln_bf16_kernel, dim3(T_TOK), dim3(256), 0, stream,
                     x, gamma, beta, xn);
  hipLaunchKernelGGL(grouped_gemm_kernel, dim3(DOUT / BN, T_TOK / BM), dim3(256),
                     0, stream, xn, W, bias, out);
}

// Round 5
// 153.058 us; speedup vs baseline: 1.3126x; 1.1727x over previous
//
#include <hip/hip_runtime.h>
#include <hip/hip_bf16.h>

// ParallelExperts: per-expert LayerNorm -> Linear(1024->4096) -> tanh-GELU
// E=16 experts, 512 tokens each (balanced), fp32 in/out, bf16 MFMA inside.

#define E_EXP 16
#define T_TOK 8192
#define DIN   1024
#define DOUT  4096

typedef __bf16 bf16;
typedef __bf16 bf16x4v __attribute__((ext_vector_type(4)));
typedef __bf16 bf16x8v __attribute__((ext_vector_type(8)));
typedef float  f32x4   __attribute__((ext_vector_type(4)));

typedef __attribute__((address_space(1))) void gvoid;
typedef __attribute__((address_space(3))) void lvoid;

// ---------------- LayerNorm -> bf16 (one block per token) ----------------
__global__ __launch_bounds__(256) void ln_bf16_kernel(
    const float* __restrict__ x, const float* __restrict__ gamma,
    const float* __restrict__ beta, bf16* __restrict__ xn) {
  const int t    = blockIdx.x;
  const int e    = t >> 9;            // 512 tokens per expert
  const int tid  = threadIdx.x;
  const float4 xv = reinterpret_cast<const float4*>(x + (size_t)t * DIN)[tid];
  float s  = xv.x + xv.y + xv.z + xv.w;
  float s2 = xv.x * xv.x + xv.y * xv.y + xv.z * xv.z + xv.w * xv.w;
#pragma unroll
  for (int o = 32; o > 0; o >>= 1) {
    s  += __shfl_xor(s,  o, 64);
    s2 += __shfl_xor(s2, o, 64);
  }
  __shared__ float red[8];
  const int lane = tid & 63, wid = tid >> 6;
  if (lane == 0) { red[wid] = s; red[4 + wid] = s2; }
  __syncthreads();
  s  = red[0] + red[1] + red[2] + red[3];
  s2 = red[4] + red[5] + red[6] + red[7];
  const float mu  = s * (1.0f / DIN);
  const float var = s2 * (1.0f / DIN) - mu * mu;
  const float inv = rsqrtf(var + 1e-5f);
  const float4 g = reinterpret_cast<const float4*>(gamma + (size_t)e * DIN)[tid];
  const float4 b = reinterpret_cast<const float4*>(beta  + (size_t)e * DIN)[tid];
  bf16x4v o;
  o[0] = (bf16)((xv.x - mu) * inv * g.x + b.x);
  o[1] = (bf16)((xv.y - mu) * inv * g.y + b.y);
  o[2] = (bf16)((xv.z - mu) * inv * g.z + b.z);
  o[3] = (bf16)((xv.w - mu) * inv * g.w + b.w);
  *reinterpret_cast<bf16x4v*>(xn + (size_t)t * DIN + tid * 4) = o;
}

// ---------------- grouped GEMM: C = GELU(xn @ W[e] + b[e]) ----------------
// 256x256 tile, BK=32, 8 waves (2m x 4n), per-wave 128x64 output
// (8x4 16x16x32 fragments -> 32 MFMA per K-step per wave).
// A (xn bf16 [m][k]): global_load_lds, linear dest, XOR-swizzled SOURCE
//   (16B-group g ^= (row>>1)&3) + matching swizzled ds_read -> 2-way free.
// B (W fp32 [k][n]): 3-deep register pipeline (load ks+3, ds_write ks+1),
//   cvt to bf16, transposed [n][KPAD] LDS. Counted vmcnt(16) at barriers
//   keeps the next B tile in flight (R4-verified FIFO accounting).
#define BM 256
#define BN 256
#define BK 32
#define NK (DIN / BK)   // 32 K-steps
#define KPAD 40         // [n][k] LDS row stride in bf16 (80 B, 16B-aligned)

#define SCHED_FENCE __builtin_amdgcn_sched_barrier(0)

__global__ __launch_bounds__(512, 2) void grouped_gemm_kernel(
    const bf16* __restrict__ xn, const float* __restrict__ W,
    const float* __restrict__ bias, float* __restrict__ out) {
  __shared__ bf16 Alds[2][BM * BK];     // 2 x 16 KB
  __shared__ bf16 Blds[2][BN * KPAD];   // 2 x 20 KB

  const int tid    = threadIdx.x;
  const int lane   = tid & 63;
  const int wid    = tid >> 6;       // 0..7
  const int warp_m = wid >> 2;       // 0..1
  const int warp_n = wid & 3;        // 0..3

  // bijective XCD swizzle: 512 blocks, 8 XCDs, 64 contiguous per XCD.
  const int swz    = (blockIdx.x & 7) * 64 + (blockIdx.x >> 3);
  const int ntile  = swz & 15;       // 0..15
  const int mtile  = swz >> 4;       // 0..31
  const int e      = mtile >> 1;     // 2 m-tiles per expert
  const int t0     = mtile * BM;
  const int n0     = ntile * BN;

  f32x4 acc[8][4];
#pragma unroll
  for (int i = 0; i < 8; ++i)
#pragma unroll
    for (int j = 0; j < 4; ++j)
      acc[i][j] = (f32x4){0.f, 0.f, 0.f, 0.f};

  const bf16*  Abase = xn + (size_t)t0 * DIN;
  const float* Wbase = W + (size_t)e * DIN * DOUT + n0;

  const int bn  = tid & 255;         // B: n column this thread owns
  const int bk0 = (tid >> 8) * 16;   // B: first k this thread covers (0 or 16)

  float s0[16], s1[16], s2[16];      // three B register sets (3-deep pipeline)

  // A staging: lane l of chunk cidx writes LDS row cidx*16+(l>>2), 16B-group
  // l&3 (HW-linear). Source fetches logical group (l&3)^((l>>3)&3) so that
  // the swizzled READ (group gL ^ (row>>1)&3) returns logical data.
  const int akg = ((lane & 3) ^ ((lane >> 3) & 3)) * 8;  // src k-offset elems

#define STAGE_A(buf, k0)                                                      \
  {                                                                           \
    _Pragma("unroll")                                                         \
    for (int c = 0; c < 2; ++c) {                                             \
      const int cidx = wid * 2 + c;                 /* 0..15 */               \
      const int row  = cidx * 16 + (lane >> 2);                               \
      const bf16* g  = Abase + (size_t)row * DIN + (k0) + akg;                \
      __builtin_amdgcn_global_load_lds((gvoid*)g,                             \
                                       (lvoid*)&Alds[buf][cidx * 512], 16, 0, 0); \
    }                                                                         \
  }

#define LOAD_B(wreg, k0)                                                      \
  {                                                                           \
    _Pragma("unroll")                                                         \
    for (int r = 0; r < 16; ++r)                                              \
      wreg[r] = Wbase[(size_t)((k0) + bk0 + r) * DOUT + bn];                  \
  }

#define WRITE_B(wreg, buf)                                                    \
  {                                                                           \
    bf16x8v v0, v1;                                                           \
    _Pragma("unroll")                                                         \
    for (int r = 0; r < 8; ++r) v0[r] = (bf16)wreg[r];                        \
    _Pragma("unroll")                                                         \
    for (int r = 0; r < 8; ++r) v1[r] = (bf16)wreg[r + 8];                    \
    *(bf16x8v*)&Blds[buf][bn * KPAD + bk0]     = v0;                          \
    *(bf16x8v*)&Blds[buf][bn * KPAD + bk0 + 8] = v1;                          \
  }

  const int swA = (lane >> 1) & 3;   // == (row>>1)&3 for this lane's rows

// One K-step body. KS may be runtime (LDS addr math); SL/SW are static
// register-set names. Issue: stage A(KS+1), load B(KS+3), MFMA(KS),
// write B(KS+1) -> LDS buf (KS+1)&1.
#define K_BODY(KS, SL, SW, STG, LDB, WRB)                                     \
  {                                                                           \
    const int ab = (KS) & 1;                                                  \
    if (STG) STAGE_A(ab ^ 1, ((KS) + 1) * BK);                                \
    SCHED_FENCE;                                                              \
    if (LDB) LOAD_B(SL, ((KS) + 3) * BK);                                     \
    SCHED_FENCE;                                                              \
    {                                                                         \
      bf16x8v af[8], bfr[4];                                                  \
      _Pragma("unroll")                                                       \
      for (int mi = 0; mi < 8; ++mi) {                                        \
        const int mrow = warp_m * 128 + mi * 16 + (lane & 15);                \
        af[mi] = *reinterpret_cast<const bf16x8v*>(                           \
            &Alds[ab][mrow * BK + (((lane >> 4) ^ swA)) * 8]);                \
      }                                                                       \
      _Pragma("unroll")                                                       \
      for (int ni = 0; ni < 4; ++ni)                                          \
        bfr[ni] = *reinterpret_cast<const bf16x8v*>(                          \
            &Blds[ab][(warp_n * 64 + ni * 16 + (lane & 15)) * KPAD +          \
                      (lane >> 4) * 8]);                                      \
      _Pragma("unroll")                                                       \
      for (int mi = 0; mi < 8; ++mi)                                          \
        _Pragma("unroll")                                                     \
        for (int ni = 0; ni < 4; ++ni)                                        \
          acc[mi][ni] = __builtin_amdgcn_mfma_f32_16x16x32_bf16(              \
              af[mi], bfr[ni], acc[mi][ni], 0, 0, 0);                         \
    }                                                                         \
    SCHED_FENCE;                                                              \
    if (WRB) WRITE_B(SW, ((KS) + 1) & 1);                                     \
  }

#define BAR_VM(N)                                                             \
  {                                                                           \
    SCHED_FENCE;                                                              \
    asm volatile("s_waitcnt vmcnt(" #N ")" ::: "memory");                     \
    asm volatile("s_waitcnt lgkmcnt(0)" ::: "memory");                        \
    __builtin_amdgcn_s_barrier();                                             \
    asm volatile("" ::: "memory");                                            \
  }

  // ---- prologue: A t0 staged; B t0,t1,t2 loaded; B t0 written ----
  STAGE_A(0, 0);                 // A t0 (2 VMEM)
  SCHED_FENCE;
  LOAD_B(s0, 0);                 // B t0 (16)
  SCHED_FENCE;
  LOAD_B(s1, BK);                // B t1 (16)
  SCHED_FENCE;
  LOAD_B(s2, 2 * BK);            // B t2 (16)
  SCHED_FENCE;
  WRITE_B(s0, 0);                // auto-waits B t0 (drains A t0, FIFO-older)
  BAR_VM(32);                    // in flight: B t1 + B t2

  // Steady state (iter ks): stage A(ks+1)->buf^1, load B(ks+3)->s[ks%3],
  // MFMA on bufs ks&1, ds-write B(ks+1) (s[(ks+1)%3]) -> buf^1.
  // Barrier vmcnt(16): drains B(ks+2)+A(ks+1), leaves B(ks+3) in flight.
  for (int ks = 0; ks < 27; ks += 3) {
    K_BODY(ks,     s0, s1, 1, 1, 1); BAR_VM(16);
    K_BODY(ks + 1, s1, s2, 1, 1, 1); BAR_VM(16);
    K_BODY(ks + 2, s2, s0, 1, 1, 1); BAR_VM(16);
  }
  K_BODY(27, s0, s1, 1, 1, 1); BAR_VM(16);
  K_BODY(28, s1, s2, 1, 1, 1); BAR_VM(16);   // loads t31 (last)
  K_BODY(29, s2, s0, 1, 0, 1); BAR_VM(0);    // stages A t30; drain all
  K_BODY(30, s0, s1, 1, 0, 1); BAR_VM(0);    // stages A t31, writes B t31
  K_BODY(31, s1, s2, 0, 0, 0);               // final MFMA, no barrier

  // --- epilogue: + bias, tanh-GELU (jax.nn.gelu approximate=True), fp32 out ---
  // gelu(v) = 0.5 v (1 + tanh(u)) = v / (1 + exp(-2u))
  const float* be = bias + (size_t)e * DOUT;
#pragma unroll
  for (int ni = 0; ni < 4; ++ni) {
    const int col = n0 + warp_n * 64 + ni * 16 + (lane & 15);
    const float bc = be[col];
#pragma unroll
    for (int mi = 0; mi < 8; ++mi) {
#pragma unroll
      for (int rr = 0; rr < 4; ++rr) {
        const int row = t0 + warp_m * 128 + mi * 16 + (lane >> 4) * 4 + rr;
        float v = acc[mi][ni][rr] + bc;
        const float u = 0.7978845608028654f * (v + 0.044715f * v * v * v);
        v = v / (1.0f + __expf(-2.0f * u));
        out[(size_t)row * DOUT + col] = v;
      }
    }
  }
}

extern "C" void kernel_launch(void* const* d_in, const int* in_sizes, int n_in,
                              void* d_out, int out_size, void* d_ws, size_t ws_size,
                              hipStream_t stream) {
  const float* x     = (const float*)d_in[0];
  // d_in[1] = expert_frequency: balanced by construction (512 each) -> unused
  const float* gamma = (const float*)d_in[2];
  const float* beta  = (const float*)d_in[3];
  const float* W     = (const float*)d_in[4];
  const float* bias  = (const float*)d_in[5];
  float* out = (float*)d_out;
  bf16* xn   = (bf16*)d_ws;    // 8192*1024 bf16 = 16 MiB scratch

  hipLaunchKernelGGL(ln_bf16_kernel, dim3(T_TOK), dim3(256), 0, stream,
                     x, gamma, beta, xn);
  hipLaunchKernelGGL(grouped_gemm_kernel, dim3((T_TOK / BM) * (DOUT / BN)),
                     dim3(512), 0, stream, xn, W, bias, out);
}